// Round 1
// baseline (111.928 us; speedup 1.0000x reference)
//
#include <hip/hip_runtime.h>
#include <hip/hip_bf16.h>
#include <math.h>

// Problem constants (from reference setup_inputs):
//   image_feats: (128, 64, 128) fp32 -> F0: 128 rows x 8192
//   lang_feats:  (128, 32, 128) fp32 -> F1: 128 rows x 4096
//   temperature: scalar fp32
// Output: (128,) fp32 = column sums of exp(A_g)*(A_g - A_f)

#define NROW 128
#define PAIRS (NROW * NROW)
#define D0 8192
#define D1 4096
#define LDS_STRIDE 132   // words per k-slice: 128 rows + 4 pad (keeps 16B alignment for b128)

// ---------------------------------------------------------------------------
// Kernel 1: split-K Gram partials. One workgroup covers ALL 128x128 pairs for
// its K-chunk of CK columns (CK multiple of 64). 256 threads as 16x16 grid,
// each thread owns an 8x8 register tile. LDS layout is k-major so fragment
// reads are contiguous ds_read_b128.
// ---------------------------------------------------------------------------
__global__ __launch_bounds__(256) void k_gram_partial(
    const float* __restrict__ F0, const float* __restrict__ F1,
    float* __restrict__ partials, int CK, int nchunk0)
{
    __shared__ float lds[64 * LDS_STRIDE];   // 33.8 KB

    const int b = blockIdx.x;
    const float* F;
    int D, chunk;
    if (b < nchunk0) { F = F0; D = D0; chunk = b; }
    else             { F = F1; D = D1; chunk = b - nchunk0; }

    float* __restrict__ pout = partials + (size_t)b * PAIRS;

    const int t  = threadIdx.x;
    const int ti = t >> 4;        // 0..15
    const int tj = t & 15;        // 0..15
    const int i0 = ti * 8;
    const int j0 = tj * 8;

    float acc[8][8];
#pragma unroll
    for (int p = 0; p < 8; ++p)
#pragma unroll
        for (int q = 0; q < 8; ++q) acc[p][q] = 0.0f;

    const int nsub = CK >> 6;
    for (int sub = 0; sub < nsub; ++sub) {
        const int k0 = chunk * CK + sub * 64;

        // ---- stage 128 rows x 64 cols into LDS (k-major, transposed) ----
        {
            const int rr = t >> 4;   // 0..15
            const int cq = t & 15;   // 0..15 -> 4 floats each
#pragma unroll
            for (int it = 0; it < 8; ++it) {
                const int r = it * 16 + rr;
                const float4 v = *(const float4*)(F + (size_t)r * D + k0 + cq * 4);
                const int c = cq * 4;
                lds[(c + 0) * LDS_STRIDE + r] = v.x;
                lds[(c + 1) * LDS_STRIDE + r] = v.y;
                lds[(c + 2) * LDS_STRIDE + r] = v.z;
                lds[(c + 3) * LDS_STRIDE + r] = v.w;
            }
        }
        __syncthreads();

        // ---- accumulate Gram over 64 k's, per-thread k rotation ----
        for (int k = 0; k < 64; ++k) {
            const int ke = (k + tj) & 63;
            const float* row = lds + ke * LDS_STRIDE;
            const float4 a0 = *(const float4*)(row + i0);
            const float4 a1 = *(const float4*)(row + i0 + 4);
            const float4 b0 = *(const float4*)(row + j0);
            const float4 b1 = *(const float4*)(row + j0 + 4);
            const float a[8]  = {a0.x, a0.y, a0.z, a0.w, a1.x, a1.y, a1.z, a1.w};
            const float bb[8] = {b0.x, b0.y, b0.z, b0.w, b1.x, b1.y, b1.z, b1.w};
#pragma unroll
            for (int p = 0; p < 8; ++p)
#pragma unroll
                for (int q = 0; q < 8; ++q)
                    acc[p][q] += a[p] * bb[q];
        }
        __syncthreads();
    }

    // ---- write 8x8 partial tile ----
#pragma unroll
    for (int p = 0; p < 8; ++p) {
        float4* dst = (float4*)(pout + (size_t)(i0 + p) * NROW + j0);
        dst[0] = make_float4(acc[p][0], acc[p][1], acc[p][2], acc[p][3]);
        dst[1] = make_float4(acc[p][4], acc[p][5], acc[p][6], acc[p][7]);
    }
}

// ---------------------------------------------------------------------------
// Kernel 2: reduce split-K partials -> G (2 sets x 128 x 128)
// ---------------------------------------------------------------------------
__global__ __launch_bounds__(256) void k_reduce(
    const float* __restrict__ partials, float* __restrict__ G,
    int nchunk0, int nchunk1)
{
    const int e   = blockIdx.x * 256 + threadIdx.x;  // 0..32767
    const int set = e >> 14;
    const int idx = e & (PAIRS - 1);
    const int cs  = set ? nchunk0 : 0;
    const int nc  = set ? nchunk1 : nchunk0;
    const float* p = partials + (size_t)cs * PAIRS + idx;
    float s = 0.0f;
    for (int c = 0; c < nc; ++c) s += p[(size_t)c * PAIRS];
    G[e] = s;
}

// ---------------------------------------------------------------------------
// Kernel 3: per-row log-softmax (both sets) + KL + column-sum atomics.
// One block per row i, 128 threads (thread = column j).
// ---------------------------------------------------------------------------
__device__ __forceinline__ float waveMax64(float v) {
#pragma unroll
    for (int off = 32; off > 0; off >>= 1) v = fmaxf(v, __shfl_xor(v, off, 64));
    return v;
}
__device__ __forceinline__ float waveSum64(float v) {
#pragma unroll
    for (int off = 32; off > 0; off >>= 1) v += __shfl_xor(v, off, 64);
    return v;
}
__device__ __forceinline__ float blockMax128(float v, float* red) {
    v = waveMax64(v);
    const int w = threadIdx.x >> 6;
    if ((threadIdx.x & 63) == 0) red[w] = v;
    __syncthreads();
    const float r = fmaxf(red[0], red[1]);
    __syncthreads();
    return r;
}
__device__ __forceinline__ float blockSum128(float v, float* red) {
    v = waveSum64(v);
    const int w = threadIdx.x >> 6;
    if ((threadIdx.x & 63) == 0) red[w] = v;
    __syncthreads();
    const float r = red[0] + red[1];
    __syncthreads();
    return r;
}

__global__ __launch_bounds__(128) void k_kl(
    const float* __restrict__ G, const float* __restrict__ temp,
    float* __restrict__ out)
{
    __shared__ float red[2];
    const int i = blockIdx.x;
    const int j = threadIdx.x;
    const float et = expf(temp[0]);

    const float* Gf = G;
    const float* Gg = G + PAIRS;

    float Af, Ag;
    {
        const float gij = Gf[i * NROW + j];
        const float gii = Gf[i * NROW + i];
        const float gjj = Gf[j * NROW + j];
        const float sq  = gii + gjj - 2.0f * gij;       // exactly 0 on diagonal
        const float dist = sq > 0.0f ? sqrtf(sq) : 0.0f;
        const float pre  = -dist * et;
        const float m = blockMax128(pre, red);
        const float s = blockSum128(expf(pre - m), red);
        Af = pre - (m + logf(s));
    }
    {
        const float gij = Gg[i * NROW + j];
        const float gii = Gg[i * NROW + i];
        const float gjj = Gg[j * NROW + j];
        const float sq  = gii + gjj - 2.0f * gij;
        const float dist = sq > 0.0f ? sqrtf(sq) : 0.0f;
        const float pre  = -dist * et;
        const float m = blockMax128(pre, red);
        const float s = blockSum128(expf(pre - m), red);
        Ag = pre - (m + logf(s));
    }
    const float kl = expf(Ag) * (Ag - Af);
    atomicAdd(out + j, kl);   // column sum over i
}

// ---------------------------------------------------------------------------
extern "C" void kernel_launch(void* const* d_in, const int* in_sizes, int n_in,
                              void* d_out, int out_size, void* d_ws, size_t ws_size,
                              hipStream_t stream)
{
    const float* img  = (const float*)d_in[0];
    const float* lng  = (const float*)d_in[1];
    const float* temp = (const float*)d_in[2];
    float* out = (float*)d_out;

    // Pick largest chunking (most parallelism) that fits the workspace.
    // need(CK) = ((8192+4096)/CK * 16384 + 32768) * 4 bytes
    int CK = 64;
    for (;;) {
        const int nc0 = D0 / CK, nc1 = D1 / CK;
        const size_t need = ((size_t)(nc0 + nc1) * PAIRS + 2 * PAIRS) * sizeof(float);
        if (need <= ws_size || CK >= 4096) break;
        CK <<= 1;
    }
    const int nc0 = D0 / CK, nc1 = D1 / CK;

    float* partials = (float*)d_ws;
    float* G = partials + (size_t)(nc0 + nc1) * PAIRS;

    hipMemsetAsync(d_out, 0, NROW * sizeof(float), stream);
    k_gram_partial<<<nc0 + nc1, 256, 0, stream>>>(img, lng, partials, CK, nc0);
    k_reduce<<<128, 256, 0, stream>>>(partials, G, nc0, nc1);
    k_kl<<<128, 128, 0, stream>>>(G, temp, out);
}

// Round 2
// 85.310 us; speedup vs baseline: 1.3120x; 1.3120x over previous
//
#include <hip/hip_runtime.h>
#include <hip/hip_bf16.h>
#include <math.h>

// Problem constants (from reference setup_inputs):
//   image_feats: (128, 64, 128) fp32 -> F0: 128 rows x 8192
//   lang_feats:  (128, 32, 128) fp32 -> F1: 128 rows x 4096
//   temperature: scalar fp32
// Output: (128,) fp32 = column sums over i of exp(A_g)*(A_g - A_f)

#define NROW 128
#define PAIRS 16384          // 128*128
#define D0 8192
#define D1 4096
#define NC0 128              // D0 / 64
#define NC1 64               // D1 / 64
#define NCHUNK 192           // NC0 + NC1
#define ROWSTRIDE 140        // words per k-slice (swizzled 128-float row, max pos 139)

// Swizzle: pos(r) = r + 4*(r/32). Keeps 16B alignment (multiples of 4 stay
// multiples of 4), keeps any aligned 8-word fragment contiguous, and turns
// the 4-way bank conflict of b-fragment reads (8*tj vs 8*(tj+4) = +32 words)
// into a free 2-way: banks of swz(8*tj) = {0,8,16,24,4,12,20,28}*2.
__device__ __forceinline__ int swz(int r) { return r + ((r >> 5) << 2); }

// ---------------------------------------------------------------------------
// Kernel 1: split-K Gram partials. Block b = one 64-column K-chunk, covering
// ALL 128x128 pairs. 256 threads as 16x16, each owns an 8x8 register tile.
// LDS is k-major (transposed) so fragment reads are ds_read_b128.
// Also writes per-chunk diagonal partials, and block 0 zeroes d_out.
// ---------------------------------------------------------------------------
__global__ __launch_bounds__(256) void k_gram(
    const float* __restrict__ F0, const float* __restrict__ F1,
    float* __restrict__ partials, float* __restrict__ diagP,
    float* __restrict__ out)
{
    __shared__ float lds[64 * ROWSTRIDE];   // 35 KB

    const int b = blockIdx.x;
    const int t = threadIdx.x;
    if (b == 0 && t < NROW) out[t] = 0.0f;  // zero output for k_kl atomics

    const float* F; int D, chunk;
    if (b < NC0) { F = F0; D = D0; chunk = b; }
    else         { F = F1; D = D1; chunk = b - NC0; }
    const int k0 = chunk * 64;

    // ---- stage 128 rows x 64 cols, transposed + swizzled ----
    {
        const int rr = t >> 4;           // 0..15
        const int c4 = (t & 15) * 4;     // 0..60 step 4
#pragma unroll
        for (int it = 0; it < 8; ++it) {
            const int r = it * 16 + rr;
            const float4 v = *(const float4*)(F + (size_t)r * D + k0 + c4);
            const int p = swz(r);
            lds[(c4 + 0) * ROWSTRIDE + p] = v.x;
            lds[(c4 + 1) * ROWSTRIDE + p] = v.y;
            lds[(c4 + 2) * ROWSTRIDE + p] = v.z;
            lds[(c4 + 3) * ROWSTRIDE + p] = v.w;
        }
    }
    __syncthreads();

    const int ti = t >> 4, tj = t & 15;
    const int i0 = ti * 8, j0 = tj * 8;
    const int ia = swz(i0);              // 8-word fragment stays contiguous
    const int ib = swz(j0);

    float acc[8][8];
#pragma unroll
    for (int p = 0; p < 8; ++p)
#pragma unroll
        for (int q = 0; q < 8; ++q) acc[p][q] = 0.0f;

#pragma unroll 8
    for (int k = 0; k < 64; ++k) {
        const float* row = lds + k * ROWSTRIDE;
        const float4 a0 = *(const float4*)(row + ia);
        const float4 a1 = *(const float4*)(row + ia + 4);
        const float4 b0 = *(const float4*)(row + ib);
        const float4 b1 = *(const float4*)(row + ib + 4);
        const float a[8]  = {a0.x, a0.y, a0.z, a0.w, a1.x, a1.y, a1.z, a1.w};
        const float bb[8] = {b0.x, b0.y, b0.z, b0.w, b1.x, b1.y, b1.z, b1.w};
#pragma unroll
        for (int p = 0; p < 8; ++p)
#pragma unroll
            for (int q = 0; q < 8; ++q)
                acc[p][q] = fmaf(a[p], bb[q], acc[p][q]);
    }

    float* __restrict__ pout = partials + (size_t)b * PAIRS;
#pragma unroll
    for (int p = 0; p < 8; ++p) {
        float4* dst = (float4*)(pout + (i0 + p) * NROW + j0);
        dst[0] = make_float4(acc[p][0], acc[p][1], acc[p][2], acc[p][3]);
        dst[1] = make_float4(acc[p][4], acc[p][5], acc[p][6], acc[p][7]);
    }
    if (ti == tj) {                       // diagonal tile: stash diag partials
        float* dd = diagP + b * NROW + i0;
#pragma unroll
        for (int p = 0; p < 8; ++p) dd[p] = acc[p][p];
    }
}

// ---------------------------------------------------------------------------
// Kernel 2 (fused): split-K reduce for row i + diag, per-row log-softmax for
// both sets, KL, column-sum atomics. Block = row i, thread = column j.
// Diagonal exactness: gij (from partials) and gjj/gii (from diagP) are the
// same stored values summed in the same ascending-c order -> bitwise equal,
// so sq = gii + gjj - 2*gij == 0 exactly on the diagonal.
// ---------------------------------------------------------------------------
__device__ __forceinline__ float waveMax64(float v) {
#pragma unroll
    for (int off = 32; off > 0; off >>= 1) v = fmaxf(v, __shfl_xor(v, off, 64));
    return v;
}
__device__ __forceinline__ float waveSum64(float v) {
#pragma unroll
    for (int off = 32; off > 0; off >>= 1) v += __shfl_xor(v, off, 64);
    return v;
}
__device__ __forceinline__ float blockMax128(float v, float* red) {
    v = waveMax64(v);
    if ((threadIdx.x & 63) == 0) red[threadIdx.x >> 6] = v;
    __syncthreads();
    const float r = fmaxf(red[0], red[1]);
    __syncthreads();
    return r;
}
__device__ __forceinline__ float blockSum128(float v, float* red) {
    v = waveSum64(v);
    if ((threadIdx.x & 63) == 0) red[threadIdx.x >> 6] = v;
    __syncthreads();
    const float r = red[0] + red[1];
    __syncthreads();
    return r;
}

__global__ __launch_bounds__(128) void k_kl(
    const float* __restrict__ partials, const float* __restrict__ diagP,
    const float* __restrict__ temp, float* __restrict__ out)
{
    __shared__ float diag[NROW];
    __shared__ float red[2];
    const int i = blockIdx.x;
    const int j = threadIdx.x;
    const float et = expf(temp[0]);

    float A[2];
#pragma unroll
    for (int s = 0; s < 2; ++s) {
        const float* Ps = partials + (s ? (size_t)NC0 * PAIRS : 0);
        const float* Ds = diagP + (s ? NC0 * NROW : 0);
        const int nc = s ? NC1 : NC0;

        float gij = 0.0f, gjj = 0.0f;
        for (int c = 0; c < nc; ++c) {
            gij += Ps[c * PAIRS + i * NROW + j];
            gjj += Ds[c * NROW + j];
        }
        diag[j] = gjj;
        __syncthreads();
        const float gii = diag[i];
        __syncthreads();

        const float sq = gii + gjj - 2.0f * gij;    // exactly 0 when i==j
        const float dist = sq > 0.0f ? sqrtf(sq) : 0.0f;
        const float pre = -dist * et;
        const float m = blockMax128(pre, red);
        const float ssum = blockSum128(expf(pre - m), red);
        A[s] = pre - (m + logf(ssum));
    }
    const float kl = expf(A[1]) * (A[1] - A[0]);    // exp(Ag)*(Ag - Af)
    atomicAdd(out + j, kl);                          // column sum over i
}

// ---------------------------------------------------------------------------
extern "C" void kernel_launch(void* const* d_in, const int* in_sizes, int n_in,
                              void* d_out, int out_size, void* d_ws, size_t ws_size,
                              hipStream_t stream)
{
    const float* img  = (const float*)d_in[0];
    const float* lng  = (const float*)d_in[1];
    const float* temp = (const float*)d_in[2];
    float* out = (float*)d_out;

    float* partials = (float*)d_ws;                       // 192*16384 floats = 12.6 MB
    float* diagP    = partials + (size_t)NCHUNK * PAIRS;  // 192*128 floats

    k_gram<<<NCHUNK, 256, 0, stream>>>(img, lng, partials, diagP, out);
    k_kl<<<NROW, NROW, 0, stream>>>(partials, diagP, temp, out);
}